// Round 8
// baseline (486.849 us; speedup 1.0000x reference)
//
#include <hip/hip_runtime.h>
#include <math.h>

#define N_NODES 50000
#define E_EDGES 500000
#define D 32
#define ED 16
#define NBLK 2048
#define NW_TOTAL (NBLK * 4)

typedef float vf4 __attribute__((ext_vector_type(4)));

__device__ __forceinline__ int2 ld_idx(const int* __restrict__ eidx, long long e) {
    int2 rc;
    rc.x = eidx[e];            // row
    rc.y = eidx[E_EDGES + e];  // col
    return rc;
}

__global__ __launch_bounds__(256) void edge_kernel(
    const float* __restrict__ h, const float* __restrict__ edge_attr,
    const float* __restrict__ Q, const float* __restrict__ W1,
    const float* __restrict__ b1, const float* __restrict__ W2,
    const float* __restrict__ b2, const int* __restrict__ eidx,
    float* __restrict__ agg)
{
    const int lane = threadIdx.x & 63;
    const int wib  = threadIdx.x >> 6;
    const int gwave = blockIdx.x * 4 + wib;

    const int o   = lane & 31;   // output unit
    const int hh  = lane >> 5;   // reduction half
    const int g   = lane >> 3;   // Q row group (0..7)
    const int sub = lane & 7;    // Q col chunk

    // W1 columns in registers, PERMUTED to match LDS msg layout:
    // msg: [0..31]=h[row]; [32+g*4+k]=T[k*8+g]; [64..79]=edge_attr; [80..111]=hidden
    float w1c[40];
#pragma unroll
    for (int i = 0; i < 40; ++i) {
        const int p = hh * 40 + i;
        int f;
        if (p < 32)      f = p;
        else if (p < 64) f = 32 + ((p - 32) & 3) * 8 + ((p - 32) >> 2);
        else             f = p;
        w1c[i] = W1[f * D + o];
    }
    float w2c[16];
#pragma unroll
    for (int i = 0; i < 16; ++i) w2c[i] = W2[(hh * 16 + i) * D + o];
    const float b1o = b1[o];
    const float b2o = b2[o];

    __shared__ __align__(16) float msg_s[4][112];
    float* m = msg_s[wib];

    struct Stage { vf4 q0, q1, q2, q3, hc, st; };

    auto issue = [&](Stage& S, long long ee, int row, int col)
        __attribute__((always_inline)) {
        const float* qe = Q + (size_t)ee * (D * D);
        S.hc = *(const vf4*)(h + (size_t)col * D + sub * 4);
        if (lane < 12) {
            const float* gsrc = (lane < 8)
                ? (h + (size_t)row * D + lane * 4)
                : (edge_attr + (size_t)ee * ED + (lane - 8) * 4);
            S.st = *(const vf4*)gsrc;
        }
        S.q0 = __builtin_nontemporal_load((const vf4*)(qe + 0 * 256 + lane * 4));
        S.q1 = __builtin_nontemporal_load((const vf4*)(qe + 1 * 256 + lane * 4));
        S.q2 = __builtin_nontemporal_load((const vf4*)(qe + 2 * 256 + lane * 4));
        S.q3 = __builtin_nontemporal_load((const vf4*)(qe + 3 * 256 + lane * 4));
    };

    auto compute = [&](const Stage& S, int row)
        __attribute__((always_inline)) {
        // write-late staging of h[row] / edge_attr
        if (lane < 12) {
            float* dst = (lane < 8) ? (m + lane * 4) : (m + 64 + (lane - 8) * 4);
            *(vf4*)dst = S.st;
        }
        // sheaf transport partials
        float a0 = S.q0.x * S.hc.x + S.q0.y * S.hc.y + S.q0.z * S.hc.z + S.q0.w * S.hc.w;
        float a1 = S.q1.x * S.hc.x + S.q1.y * S.hc.y + S.q1.z * S.hc.z + S.q1.w * S.hc.w;
        float a2 = S.q2.x * S.hc.x + S.q2.y * S.hc.y + S.q2.z * S.hc.z + S.q2.w * S.hc.w;
        float a3 = S.q3.x * S.hc.x + S.q3.y * S.hc.y + S.q3.z * S.hc.z + S.q3.w * S.hc.w;
#pragma unroll
        for (int mm = 1; mm <= 4; mm <<= 1) {
            a0 += __shfl_xor(a0, mm);
            a1 += __shfl_xor(a1, mm);
            a2 += __shfl_xor(a2, mm);
            a3 += __shfl_xor(a3, mm);
        }
        if (sub == 0) {
            vf4 t; t.x = a0; t.y = a1; t.z = a2; t.w = a3;
            *(vf4*)(m + 32 + g * 4) = t;   // permuted layout matches w1c
        }
        // MLP layer 1
        float s = 0.f;
        const vf4* mv = (const vf4*)(m + hh * 40);
#pragma unroll
        for (int i4 = 0; i4 < 10; ++i4) {
            const vf4 v = mv[i4];
            s = fmaf(v.x, w1c[4 * i4 + 0], s);
            s = fmaf(v.y, w1c[4 * i4 + 1], s);
            s = fmaf(v.z, w1c[4 * i4 + 2], s);
            s = fmaf(v.w, w1c[4 * i4 + 3], s);
        }
        s += __shfl_xor(s, 32);
        s = fmaxf(s + b1o, 0.f);
        if (lane < 32) m[80 + o] = s;
        // MLP layer 2
        float t = 0.f;
        const vf4* hv = (const vf4*)(m + 80 + hh * 16);
#pragma unroll
        for (int i4 = 0; i4 < 4; ++i4) {
            const vf4 v = hv[i4];
            t = fmaf(v.x, w2c[4 * i4 + 0], t);
            t = fmaf(v.y, w2c[4 * i4 + 1], t);
            t = fmaf(v.z, w2c[4 * i4 + 2], t);
            t = fmaf(v.w, w2c[4 * i4 + 3], t);
        }
        t += __shfl_xor(t, 32);
        t += b2o;
        if (lane < 32) atomicAdd(&agg[(size_t)row * D + o], t);
    };

    const long long nw = NW_TOTAL;
    long long e = gwave;
    if (e >= E_EDGES) return;

    // ---- 3-deep pipeline: prefetch distance = 2 bodies (~1000+ cyc) ----
    Stage A, B, C;
    int2 rcA, rcB, rcC;
    rcA = ld_idx(eidx, e);
    issue(A, e, rcA.x, rcA.y);

    const long long eB0 = e + nw;
    const bool hB0 = eB0 < E_EDGES;
    if (hB0) { rcB = ld_idx(eidx, eB0); issue(B, eB0, rcB.x, rcB.y); }

    const long long eC0 = e + 2 * nw;
    const bool hC0 = eC0 < E_EDGES;
    if (hC0) { rcC = ld_idx(eidx, eC0); issue(C, eC0, rcC.x, rcC.y); }

    while (true) {
        {   // body A: computes edge e, refills A with e+3nw
            const long long e3 = e + 3 * nw;
            const bool h3 = e3 < E_EDGES;
            int2 rc3 = make_int2(0, 0);
            if (h3) rc3 = ld_idx(eidx, e3);
            compute(A, rcA.x);
            if (h3) { issue(A, e3, rc3.x, rc3.y); rcA = rc3; }
        }
        {   // body B: computes edge e+nw, refills B with e+4nw
            const long long ec = e + nw;
            if (ec >= E_EDGES) break;
            const long long e3 = e + 4 * nw;
            const bool h3 = e3 < E_EDGES;
            int2 rc3 = make_int2(0, 0);
            if (h3) rc3 = ld_idx(eidx, e3);
            compute(B, rcB.x);
            if (h3) { issue(B, e3, rc3.x, rc3.y); rcB = rc3; }
        }
        {   // body C: computes edge e+2nw, refills C with e+5nw
            const long long ec = e + 2 * nw;
            if (ec >= E_EDGES) break;
            const long long e3 = e + 5 * nw;
            const bool h3 = e3 < E_EDGES;
            int2 rc3 = make_int2(0, 0);
            if (h3) rc3 = ld_idx(eidx, e3);
            compute(C, rcC.x);
            if (h3) { issue(C, e3, rc3.x, rc3.y); rcC = rc3; }
        }
        e += 3 * nw;
        if (e >= E_EDGES) break;
    }
}

__global__ __launch_bounds__(256) void node_kernel(
    const float* __restrict__ h, const float* __restrict__ agg,
    const float* __restrict__ Wd1, const float* __restrict__ bd1,
    const float* __restrict__ ln_g, const float* __restrict__ ln_b,
    const float* __restrict__ Wd2, const float* __restrict__ bd2,
    float* __restrict__ out)
{
    __shared__ float sWd1[64 * 32];
    __shared__ float sWd2[32 * 32];
    __shared__ float xbuf[4][64];

    for (int i = threadIdx.x; i < 64 * 32; i += 256) sWd1[i] = Wd1[i];
    for (int i = threadIdx.x; i < 32 * 32; i += 256) sWd2[i] = Wd2[i];
    __syncthreads();

    const int tid  = blockIdx.x * 256 + threadIdx.x;
    const int n    = tid >> 5;
    const int o    = tid & 31;
    const int wib  = threadIdx.x >> 6;
    const int lane = threadIdx.x & 63;
    if (n >= N_NODES) return;

    const float* hn = h   + (size_t)n * D;
    const float* an = agg + (size_t)n * D;

    float x = bd1[o];
#pragma unroll
    for (int k4 = 0; k4 < 8; ++k4) {
        const float4 hv = *reinterpret_cast<const float4*>(hn + k4 * 4);
        x = fmaf(hv.x, sWd1[(k4 * 4 + 0) * 32 + o], x);
        x = fmaf(hv.y, sWd1[(k4 * 4 + 1) * 32 + o], x);
        x = fmaf(hv.z, sWd1[(k4 * 4 + 2) * 32 + o], x);
        x = fmaf(hv.w, sWd1[(k4 * 4 + 3) * 32 + o], x);
    }
#pragma unroll
    for (int k4 = 0; k4 < 8; ++k4) {
        const float4 av = *reinterpret_cast<const float4*>(an + k4 * 4);
        x = fmaf(av.x, sWd1[(32 + k4 * 4 + 0) * 32 + o], x);
        x = fmaf(av.y, sWd1[(32 + k4 * 4 + 1) * 32 + o], x);
        x = fmaf(av.z, sWd1[(32 + k4 * 4 + 2) * 32 + o], x);
        x = fmaf(av.w, sWd1[(32 + k4 * 4 + 3) * 32 + o], x);
    }

    float mu = x;
#pragma unroll
    for (int mm = 1; mm <= 16; mm <<= 1) mu += __shfl_xor(mu, mm);
    mu *= (1.0f / 32.0f);
    const float dx = x - mu;
    float var = dx * dx;
#pragma unroll
    for (int mm = 1; mm <= 16; mm <<= 1) var += __shfl_xor(var, mm);
    var *= (1.0f / 32.0f);
    float xs = dx * rsqrtf(var + 1e-5f);
    xs = xs * ln_g[o] + ln_b[o];
    xs = xs / (1.0f + __expf(-xs));

    xbuf[wib][lane] = xs;

    float y = bd2[o];
    const float* xb = &xbuf[wib][lane & 32];
#pragma unroll
    for (int k4 = 0; k4 < 8; ++k4) {
        const float4 xv = *reinterpret_cast<const float4*>(xb + k4 * 4);
        y = fmaf(xv.x, sWd2[(k4 * 4 + 0) * 32 + o], y);
        y = fmaf(xv.y, sWd2[(k4 * 4 + 1) * 32 + o], y);
        y = fmaf(xv.z, sWd2[(k4 * 4 + 2) * 32 + o], y);
        y = fmaf(xv.w, sWd2[(k4 * 4 + 3) * 32 + o], y);
    }
    out[(size_t)n * D + o] = tanhf(y);
}

extern "C" void kernel_launch(void* const* d_in, const int* in_sizes, int n_in,
                              void* d_out, int out_size, void* d_ws, size_t ws_size,
                              hipStream_t stream) {
    const float* h         = (const float*)d_in[1];
    const float* edge_attr = (const float*)d_in[2];
    const float* Q         = (const float*)d_in[3];
    const float* W1        = (const float*)d_in[4];
    const float* b1        = (const float*)d_in[5];
    const float* W2        = (const float*)d_in[6];
    const float* b2        = (const float*)d_in[7];
    const float* Wd1       = (const float*)d_in[8];
    const float* bd1       = (const float*)d_in[9];
    const float* ln_g      = (const float*)d_in[10];
    const float* ln_b      = (const float*)d_in[11];
    const float* Wd2       = (const float*)d_in[12];
    const float* bd2       = (const float*)d_in[13];
    const int*   eidx      = (const int*)d_in[14];

    float* agg = (float*)d_ws;
    hipMemsetAsync(agg, 0, (size_t)N_NODES * D * sizeof(float), stream);

    edge_kernel<<<NBLK, 256, 0, stream>>>(h, edge_attr, Q, W1, b1, W2, b2, eidx, agg);
    node_kernel<<<(N_NODES * D + 255) / 256, 256, 0, stream>>>(
        h, agg, Wd1, bd1, ln_g, ln_b, Wd2, bd2, (float*)d_out);
}

// Round 9
// 446.850 us; speedup vs baseline: 1.0895x; 1.0895x over previous
//
#include <hip/hip_runtime.h>
#include <math.h>

#define N_NODES 50000
#define E_EDGES 500000
#define D 32
#define ED 16
#define NBLK 2048
#define NW_TOTAL (NBLK * 4)

typedef float vf4 __attribute__((ext_vector_type(4)));

struct Stage {
    vf4 q0, q1, q2, q3;   // Q[e] rows k*8+g, cols sub*4..+3 (k=0..3)
    vf4 hc;               // h[col][sub*4..+3]
    vf4 st;               // staged: lanes<8 -> h[row] chunk, lanes 8..11 -> edge_attr chunk
};

__device__ __forceinline__ int2 ld_idx(const int* __restrict__ eidx, long long e) {
    int2 rc;
    rc.x = eidx[e];            // row
    rc.y = eidx[E_EDGES + e];  // col
    return rc;
}

__global__ __launch_bounds__(256) void edge_kernel(
    const float* __restrict__ h, const float* __restrict__ edge_attr,
    const float* __restrict__ Q, const float* __restrict__ W1,
    const float* __restrict__ b1, const float* __restrict__ W2,
    const float* __restrict__ b2, const int* __restrict__ eidx,
    float* __restrict__ agg)
{
    const int lane = threadIdx.x & 63;
    const int wib  = threadIdx.x >> 6;
    const int gwave = blockIdx.x * 4 + wib;

    const int o   = lane & 31;   // output unit
    const int hh  = lane >> 5;   // reduction half
    const int g   = lane >> 3;   // Q row group (0..7)
    const int sub = lane & 7;    // Q col chunk

    // W1 columns in registers, PERMUTED to match the LDS msg layout:
    // msg: [0..31]=h[row]; [32+g*4+k]=T[k*8+g]; [64..79]=edge_attr; [80..111]=hidden
    float w1c[40];
#pragma unroll
    for (int i = 0; i < 40; ++i) {
        const int p = hh * 40 + i;
        int f;
        if (p < 32)      f = p;
        else if (p < 64) f = 32 + ((p - 32) & 3) * 8 + ((p - 32) >> 2);
        else             f = p;
        w1c[i] = W1[f * D + o];
    }
    float w2c[16];
#pragma unroll
    for (int i = 0; i < 16; ++i) w2c[i] = W2[(hh * 16 + i) * D + o];
    const float b1o = b1[o];
    const float b2o = b2[o];

    __shared__ __align__(16) float msg_s[4][112];
    float* m = msg_s[wib];

    auto issue = [&](Stage& S, long long ee, int row, int col)
        __attribute__((always_inline)) {
        const float* qe = Q + (size_t)ee * (D * D);
        S.hc = *(const vf4*)(h + (size_t)col * D + sub * 4);
        if (lane < 12) {
            const float* gsrc = (lane < 8)
                ? (h + (size_t)row * D + lane * 4)
                : (edge_attr + (size_t)ee * ED + (lane - 8) * 4);
            S.st = *(const vf4*)gsrc;
        }
        S.q0 = __builtin_nontemporal_load((const vf4*)(qe + 0 * 256 + lane * 4));
        S.q1 = __builtin_nontemporal_load((const vf4*)(qe + 1 * 256 + lane * 4));
        S.q2 = __builtin_nontemporal_load((const vf4*)(qe + 2 * 256 + lane * 4));
        S.q3 = __builtin_nontemporal_load((const vf4*)(qe + 3 * 256 + lane * 4));
    };

    auto compute = [&](const Stage& S, int row)
        __attribute__((always_inline)) {
        // write-late staging of h[row] / edge_attr
        if (lane < 12) {
            float* dst = (lane < 8) ? (m + lane * 4) : (m + 64 + (lane - 8) * 4);
            *(vf4*)dst = S.st;
        }
        // sheaf transport partials
        float a0 = S.q0.x * S.hc.x + S.q0.y * S.hc.y + S.q0.z * S.hc.z + S.q0.w * S.hc.w;
        float a1 = S.q1.x * S.hc.x + S.q1.y * S.hc.y + S.q1.z * S.hc.z + S.q1.w * S.hc.w;
        float a2 = S.q2.x * S.hc.x + S.q2.y * S.hc.y + S.q2.z * S.hc.z + S.q2.w * S.hc.w;
        float a3 = S.q3.x * S.hc.x + S.q3.y * S.hc.y + S.q3.z * S.hc.z + S.q3.w * S.hc.w;
#pragma unroll
        for (int mm = 1; mm <= 4; mm <<= 1) {
            a0 += __shfl_xor(a0, mm);
            a1 += __shfl_xor(a1, mm);
            a2 += __shfl_xor(a2, mm);
            a3 += __shfl_xor(a3, mm);
        }
        if (sub == 0) {
            vf4 t; t.x = a0; t.y = a1; t.z = a2; t.w = a3;
            *(vf4*)(m + 32 + g * 4) = t;   // permuted layout matches w1c
        }
        // MLP layer 1
        float s = 0.f;
        const vf4* mv = (const vf4*)(m + hh * 40);
#pragma unroll
        for (int i4 = 0; i4 < 10; ++i4) {
            const vf4 v = mv[i4];
            s = fmaf(v.x, w1c[4 * i4 + 0], s);
            s = fmaf(v.y, w1c[4 * i4 + 1], s);
            s = fmaf(v.z, w1c[4 * i4 + 2], s);
            s = fmaf(v.w, w1c[4 * i4 + 3], s);
        }
        s += __shfl_xor(s, 32);
        s = fmaxf(s + b1o, 0.f);
        if (lane < 32) m[80 + o] = s;
        // MLP layer 2
        float t = 0.f;
        const vf4* hv = (const vf4*)(m + 80 + hh * 16);
#pragma unroll
        for (int i4 = 0; i4 < 4; ++i4) {
            const vf4 v = hv[i4];
            t = fmaf(v.x, w2c[4 * i4 + 0], t);
            t = fmaf(v.y, w2c[4 * i4 + 1], t);
            t = fmaf(v.z, w2c[4 * i4 + 2], t);
            t = fmaf(v.w, w2c[4 * i4 + 3], t);
        }
        t += __shfl_xor(t, 32);
        t += b2o;
        if (lane < 32) atomicAdd(&agg[(size_t)row * D + o], t);
    };

    const long long nw = NW_TOTAL;
    long long e = gwave;
    if (e >= E_EDGES) return;

    Stage A, B;
    vf4 dummy;
    int2 rc_cur = ld_idx(eidx, e);
    issue(A, e, rc_cur.x, rc_cur.y);

    long long en = e + nw;
    bool haveN = en < E_EDGES;
    int2 rc_nxt = make_int2(0, 0);
    if (haveN) {
        rc_nxt = ld_idx(eidx, en);
        issue(B, en, rc_nxt.x, rc_nxt.y);
    }

    while (true) {
        {   // body A (edge e): compute stage A, refill A with e+2nw
            const long long e2 = e + 2 * nw;
            const bool have2 = e2 < E_EDGES;
            int2 rc2 = make_int2(0, 0);
            if (have2) rc2 = ld_idx(eidx, e2);
            compute(A, rc_cur.x);
            if (have2) issue(A, e2, rc2.x, rc2.y);
            rc_cur = rc_nxt; rc_nxt = rc2;
            e = en; en = e + nw;
            if (e >= E_EDGES) break;
        }
        {   // body B (edge e): compute stage B, refill B with e+2nw
            const long long e2 = e + 2 * nw;
            const bool have2 = e2 < E_EDGES;
            int2 rc2 = make_int2(0, 0);
            if (have2) rc2 = ld_idx(eidx, e2);
            compute(B, rc_cur.x);
            if (have2) issue(B, e2, rc2.x, rc2.y);
            rc_cur = rc_nxt; rc_nxt = rc2;
            e = en; en = e + nw;
            if (e >= E_EDGES) break;
        }
    }
}

__global__ __launch_bounds__(256) void node_kernel(
    const float* __restrict__ h, const float* __restrict__ agg,
    const float* __restrict__ Wd1, const float* __restrict__ bd1,
    const float* __restrict__ ln_g, const float* __restrict__ ln_b,
    const float* __restrict__ Wd2, const float* __restrict__ bd2,
    float* __restrict__ out)
{
    __shared__ float sWd1[64 * 32];
    __shared__ float sWd2[32 * 32];
    __shared__ float xbuf[4][64];

    for (int i = threadIdx.x; i < 64 * 32; i += 256) sWd1[i] = Wd1[i];
    for (int i = threadIdx.x; i < 32 * 32; i += 256) sWd2[i] = Wd2[i];
    __syncthreads();

    const int tid  = blockIdx.x * 256 + threadIdx.x;
    const int n    = tid >> 5;
    const int o    = tid & 31;
    const int wib  = threadIdx.x >> 6;
    const int lane = threadIdx.x & 63;
    if (n >= N_NODES) return;

    const float* hn = h   + (size_t)n * D;
    const float* an = agg + (size_t)n * D;

    float x = bd1[o];
#pragma unroll
    for (int k4 = 0; k4 < 8; ++k4) {
        const float4 hv = *reinterpret_cast<const float4*>(hn + k4 * 4);
        x = fmaf(hv.x, sWd1[(k4 * 4 + 0) * 32 + o], x);
        x = fmaf(hv.y, sWd1[(k4 * 4 + 1) * 32 + o], x);
        x = fmaf(hv.z, sWd1[(k4 * 4 + 2) * 32 + o], x);
        x = fmaf(hv.w, sWd1[(k4 * 4 + 3) * 32 + o], x);
    }
#pragma unroll
    for (int k4 = 0; k4 < 8; ++k4) {
        const float4 av = *reinterpret_cast<const float4*>(an + k4 * 4);
        x = fmaf(av.x, sWd1[(32 + k4 * 4 + 0) * 32 + o], x);
        x = fmaf(av.y, sWd1[(32 + k4 * 4 + 1) * 32 + o], x);
        x = fmaf(av.z, sWd1[(32 + k4 * 4 + 2) * 32 + o], x);
        x = fmaf(av.w, sWd1[(32 + k4 * 4 + 3) * 32 + o], x);
    }

    float mu = x;
#pragma unroll
    for (int mm = 1; mm <= 16; mm <<= 1) mu += __shfl_xor(mu, mm);
    mu *= (1.0f / 32.0f);
    const float dx = x - mu;
    float var = dx * dx;
#pragma unroll
    for (int mm = 1; mm <= 16; mm <<= 1) var += __shfl_xor(var, mm);
    var *= (1.0f / 32.0f);
    float xs = dx * rsqrtf(var + 1e-5f);
    xs = xs * ln_g[o] + ln_b[o];
    xs = xs / (1.0f + __expf(-xs));

    xbuf[wib][lane] = xs;

    float y = bd2[o];
    const float* xb = &xbuf[wib][lane & 32];
#pragma unroll
    for (int k4 = 0; k4 < 8; ++k4) {
        const float4 xv = *reinterpret_cast<const float4*>(xb + k4 * 4);
        y = fmaf(xv.x, sWd2[(k4 * 4 + 0) * 32 + o], y);
        y = fmaf(xv.y, sWd2[(k4 * 4 + 1) * 32 + o], y);
        y = fmaf(xv.z, sWd2[(k4 * 4 + 2) * 32 + o], y);
        y = fmaf(xv.w, sWd2[(k4 * 4 + 3) * 32 + o], y);
    }
    out[(size_t)n * D + o] = tanhf(y);
}

extern "C" void kernel_launch(void* const* d_in, const int* in_sizes, int n_in,
                              void* d_out, int out_size, void* d_ws, size_t ws_size,
                              hipStream_t stream) {
    const float* h         = (const float*)d_in[1];
    const float* edge_attr = (const float*)d_in[2];
    const float* Q         = (const float*)d_in[3];
    const float* W1        = (const float*)d_in[4];
    const float* b1        = (const float*)d_in[5];
    const float* W2        = (const float*)d_in[6];
    const float* b2        = (const float*)d_in[7];
    const float* Wd1       = (const float*)d_in[8];
    const float* bd1       = (const float*)d_in[9];
    const float* ln_g      = (const float*)d_in[10];
    const float* ln_b      = (const float*)d_in[11];
    const float* Wd2       = (const float*)d_in[12];
    const float* bd2       = (const float*)d_in[13];
    const int*   eidx      = (const int*)d_in[14];

    float* agg = (float*)d_ws;
    hipMemsetAsync(agg, 0, (size_t)N_NODES * D * sizeof(float), stream);

    edge_kernel<<<NBLK, 256, 0, stream>>>(h, edge_attr, Q, W1, b1, W2, b2, eidx, agg);
    node_kernel<<<(N_NODES * D + 255) / 256, 256, 0, stream>>>(
        h, agg, Wd1, bd1, ln_g, ln_b, Wd2, bd2, (float*)d_out);
}